// Round 8
// baseline (488.655 us; speedup 1.0000x reference)
//
#include <hip/hip_runtime.h>
#include <hip/hip_bf16.h>
#include <math.h>

#define N_NUC_C 100000
#define N_NN_C  1600000
#define EMB_C   128
#define MSG_C   32
#define OUT_C   128
#define NB1     98   // ceil(N_NUC / 1024) for the scan
#define NPART   8
#define R_PER_P (N_NUC_C / NPART)          // 12500 receivers per partition
#define SBLK    784                        // blocks per partition in scatter
#define STHREADS (SBLK * 256)              // 200704 threads per partition
#define LDS_USTR 17                        // uint row stride (16 packed + 1 pad, odd -> conflict-free)

__device__ __forceinline__ float silu_f(float y) {
    return y / (1.0f + __expf(-y));
}

// round-to-nearest-even f32->bf16, packed pair (a -> low 16, b -> high 16)
__device__ __forceinline__ unsigned pack_bf16x2(float a, float b) {
    unsigned ua = __float_as_uint(a); ua += 0x7FFFu + ((ua >> 16) & 1u);
    unsigned ub = __float_as_uint(b); ub += 0x7FFFu + ((ub >> 16) & 1u);
    return (ua >> 16) | (ub & 0xFFFF0000u);
}

// ---------------------------------------------------------------------------
// Kernel A: node projections  proj[pr][n][c] = embed[n] @ W + b
// ---------------------------------------------------------------------------
__global__ __launch_bounds__(256) void proj_kernel(
    const float* __restrict__ s_embed, const float* __restrict__ r_embed,
    const float* __restrict__ W_s, const float* __restrict__ b_s,
    const float* __restrict__ W_r, const float* __restrict__ b_r,
    float* __restrict__ proj /* [2][N_NUC][MSG] */)
{
    const int n   = blockIdx.x * blockDim.x + threadIdx.x;
    const int sub = blockIdx.y;       // 0..3
    const int pr  = sub >> 1;
    const int c0  = (sub & 1) * 16;
    if (n >= N_NUC_C) return;

    const float* __restrict__ src = pr ? r_embed : s_embed;
    const float* __restrict__ W   = pr ? W_r : W_s;
    const float* __restrict__ b   = pr ? b_r : b_s;
    float* __restrict__ dst = proj + (size_t)pr * N_NUC_C * MSG_C;

    float acc[16];
    #pragma unroll
    for (int i = 0; i < 16; ++i) acc[i] = b[c0 + i];

    const float* row = src + (size_t)n * EMB_C;
    #pragma unroll 4
    for (int k = 0; k < EMB_C; k += 4) {
        const float4 rv = *reinterpret_cast<const float4*>(row + k);
        #pragma unroll
        for (int i = 0; i < 16; ++i) {
            acc[i] = fmaf(rv.x, W[(k + 0) * MSG_C + c0 + i], acc[i]);
            acc[i] = fmaf(rv.y, W[(k + 1) * MSG_C + c0 + i], acc[i]);
            acc[i] = fmaf(rv.z, W[(k + 2) * MSG_C + c0 + i], acc[i]);
            acc[i] = fmaf(rv.w, W[(k + 3) * MSG_C + c0 + i], acc[i]);
        }
    }

    float4* d = reinterpret_cast<float4*>(dst + (size_t)n * MSG_C + c0);
    d[0] = make_float4(acc[0],  acc[1],  acc[2],  acc[3]);
    d[1] = make_float4(acc[4],  acc[5],  acc[6],  acc[7]);
    d[2] = make_float4(acc[8],  acc[9],  acc[10], acc[11]);
    d[3] = make_float4(acc[12], acc[13], acc[14], acc[15]);
}

// ---------------------------------------------------------------------------
// CSR build: single atomic pass — rank[e] = running index within receiver
// ---------------------------------------------------------------------------
__global__ __launch_bounds__(256) void rank_kernel(
    const int* __restrict__ receivers, int* __restrict__ cnt,
    int* __restrict__ rank)
{
    const int e = blockIdx.x * blockDim.x + threadIdx.x;
    if (e >= N_NN_C) return;
    rank[e] = atomicAdd(&cnt[receivers[e]], 1);
}

// Exclusive scan of cnt[N_NUC] -> offsets. Three tiny kernels.
__global__ __launch_bounds__(256) void scan1_kernel(
    const int* __restrict__ cnt, int* __restrict__ excl, int* __restrict__ blockTot)
{
    __shared__ int waveTot[4];
    const int t = threadIdx.x, b = blockIdx.x;
    const int lane = t & 63, wid = t >> 6;
    const int base = b * 1024 + t * 4;

    int d0 = (base + 0 < N_NUC_C) ? cnt[base + 0] : 0;
    int d1 = (base + 1 < N_NUC_C) ? cnt[base + 1] : 0;
    int d2 = (base + 2 < N_NUC_C) ? cnt[base + 2] : 0;
    int d3 = (base + 3 < N_NUC_C) ? cnt[base + 3] : 0;
    const int s = d0 + d1 + d2 + d3;

    int incl = s;
    #pragma unroll
    for (int off = 1; off < 64; off <<= 1) {
        int v = __shfl_up(incl, off);
        if (lane >= off) incl += v;
    }
    const int wexcl = incl - s;
    if (lane == 63) waveTot[wid] = incl;
    __syncthreads();
    int wbase = 0;
    for (int w = 0; w < wid; ++w) wbase += waveTot[w];
    const int e0 = wbase + wexcl;

    if (base + 0 < N_NUC_C) excl[base + 0] = e0;
    if (base + 1 < N_NUC_C) excl[base + 1] = e0 + d0;
    if (base + 2 < N_NUC_C) excl[base + 2] = e0 + d0 + d1;
    if (base + 3 < N_NUC_C) excl[base + 3] = e0 + d0 + d1 + d2;
    if (t == 255) blockTot[b] = wbase + incl;
}

__global__ __launch_bounds__(128) void scan2_kernel(
    const int* __restrict__ blockTot, int* __restrict__ blockOff)
{
    __shared__ int sh[128];
    const int t = threadIdx.x;
    const int v = (t < NB1) ? blockTot[t] : 0;
    sh[t] = v;
    __syncthreads();
    #pragma unroll
    for (int off = 1; off < 128; off <<= 1) {
        int x = 0;
        if (t >= off) x = sh[t - off];
        __syncthreads();
        sh[t] += x;
        __syncthreads();
    }
    if (t < NB1) blockOff[t] = sh[t] - v;
}

__global__ __launch_bounds__(256) void scan3_kernel(
    const int* __restrict__ excl, const int* __restrict__ blockOff,
    int* __restrict__ offsets)
{
    const int n = blockIdx.x * blockDim.x + threadIdx.x;
    if (n < N_NUC_C) offsets[n] = excl[n] + blockOff[n >> 10];
    if (n == 0) offsets[N_NUC_C] = N_NN_C;
}

// ---------------------------------------------------------------------------
// Partition-local atomic-free scatter + e_embed repack.
// Blocks with blockIdx%8==p scan all edges (coalesced); for r in range p:
//   dst = offsets[r] + rank[e]  (unique)
//   pack_csr[dst] = (sender, receiver)             (8 B)
//   e_csr[dst]    = bf16-packed e_embed[e] row     (64 B, one full line)
// e_embed is read ONCE device-wide in ascending-e (quasi-sequential) order —
// this replaces fused_csr's fully-random 128 B gather (the R7 wall).
// Writes are partition-clustered -> L2 write coalescing.
// ---------------------------------------------------------------------------
__global__ __launch_bounds__(256) void scatter_pack8_kernel(
    const int* __restrict__ senders, const int* __restrict__ receivers,
    const int* __restrict__ rank, const int* __restrict__ offsets,
    const float* __restrict__ e_embed,
    int2* __restrict__ pack_csr, uint4* __restrict__ e_csr /* [N_NN][4] */)
{
    const int p    = blockIdx.x & 7;
    const int blk  = blockIdx.x >> 3;                 // 0..SBLK-1
    const int base = blk * 256 + threadIdx.x;         // 0..STHREADS-1
    const int rlo  = p * R_PER_P;
    const int rhi  = rlo + R_PER_P;

    #pragma unroll
    for (int k = 0; k < 8; ++k) {
        const int e = base + k * STHREADS;
        if (e < N_NN_C) {
            const int r = receivers[e];
            if (r >= rlo && r < rhi) {
                const int dst = offsets[r] + rank[e];
                pack_csr[dst] = make_int2(senders[e], r);
                const float4* ee = reinterpret_cast<const float4*>(e_embed + (size_t)e * MSG_C);
                uint4* d4 = e_csr + (size_t)dst * 4;
                #pragma unroll
                for (int q = 0; q < 4; ++q) {
                    const float4 a = ee[2*q];
                    const float4 b = ee[2*q + 1];
                    uint4 w;
                    w.x = pack_bf16x2(a.x, a.y);
                    w.y = pack_bf16x2(a.z, a.w);
                    w.z = pack_bf16x2(b.x, b.y);
                    w.w = pack_bf16x2(b.z, b.w);
                    d4[q] = w;
                }
            }
        }
    }
}

// ---------------------------------------------------------------------------
// Fused CSR edge compute + in-block segmented reduction.
// Block = 256 consecutive CSR slots. ALL global reads are now sequential
// (pack_csr, e_csr, proj_r) or cache-resident random (proj_s, 25.6 MB).
// Gate matmul at full lane utilization. Messages staged in LDS as bf16x2
// (uint[256][17], odd stride -> conflict-free). Reduction in f32.
// ---------------------------------------------------------------------------
__global__ __launch_bounds__(256) void fused_csr_kernel(
    const float* __restrict__ proj,      // [2][N_NUC][MSG]
    const int2*  __restrict__ pack_csr,  // [N_NN] (s, r) CSR order
    const uint4* __restrict__ e_csr,     // [N_NN][4] bf16-packed e rows
    const int*   __restrict__ offsets,   // [N_NUC+1]
    const float* __restrict__ ln_scale,
    const float* __restrict__ ln_bias,
    const float* __restrict__ W_e,       // [MSG][MSG]
    float*       __restrict__ msg)       // [N_NUC][MSG], pre-zeroed
{
    __shared__ unsigned lds_u[256 * LDS_USTR];
    __shared__ int      lds_r[256];

    const int t  = threadIdx.x;
    const int B0 = blockIdx.x * 256;     // first slot of this block

    // ---- phase 1: per-edge message (single-shot, straight-line) ----
    const int2 pk = pack_csr[B0 + t];
    const int s = pk.x, r = pk.y;
    lds_r[t] = r;

    // sequential 64 B read of the packed edge row
    float ev[MSG_C];
    {
        const uint4* ec = e_csr + (size_t)(B0 + t) * 4;
        #pragma unroll
        for (int q = 0; q < 4; ++q) {
            const uint4 w = ec[q];
            ev[8*q+0] = __uint_as_float(w.x << 16);
            ev[8*q+1] = __uint_as_float(w.x & 0xFFFF0000u);
            ev[8*q+2] = __uint_as_float(w.y << 16);
            ev[8*q+3] = __uint_as_float(w.y & 0xFFFF0000u);
            ev[8*q+4] = __uint_as_float(w.z << 16);
            ev[8*q+5] = __uint_as_float(w.z & 0xFFFF0000u);
            ev[8*q+6] = __uint_as_float(w.w << 16);
            ev[8*q+7] = __uint_as_float(w.w & 0xFFFF0000u);
        }
    }

    const float4* ps = reinterpret_cast<const float4*>(proj + (size_t)s * MSG_C);
    const float4* pq = reinterpret_cast<const float4*>(proj + (size_t)(N_NUC_C + r) * MSG_C);

    float x[MSG_C];
    #pragma unroll
    for (int q = 0; q < 8; ++q) {
        const float4 a = ps[q];
        const float4 b = pq[q];
        x[4*q+0] = a.x + b.x; x[4*q+1] = a.y + b.y;
        x[4*q+2] = a.z + b.z; x[4*q+3] = a.w + b.w;
    }

    // gate = e @ W_e (wave-uniform W_e -> scalar operands)
    float g[MSG_C];
    #pragma unroll
    for (int c = 0; c < MSG_C; ++c) g[c] = 0.0f;
    #pragma unroll
    for (int k = 0; k < MSG_C; ++k) {
        const float ek = ev[k];
        #pragma unroll
        for (int c = 0; c < MSG_C; ++c)
            g[c] = fmaf(ek, W_e[k * MSG_C + c], g[c]);
    }

    // LayerNorm + SiLU, write packed bf16 message to LDS
    float mu = 0.0f;
    #pragma unroll
    for (int c = 0; c < MSG_C; ++c) mu += x[c];
    mu *= (1.0f / MSG_C);
    float var = 0.0f;
    #pragma unroll
    for (int c = 0; c < MSG_C; ++c) { const float d = x[c] - mu; var = fmaf(d, d, var); }
    var *= (1.0f / MSG_C);
    const float rs = rsqrtf(var + 1e-6f);

    unsigned* orow = &lds_u[t * LDS_USTR];
    #pragma unroll
    for (int i = 0; i < 16; ++i) {
        const int c0_ = 2*i, c1_ = 2*i + 1;
        const float y0 = (x[c0_] - mu) * rs * ln_scale[c0_] + ln_bias[c0_];
        const float y1 = (x[c1_] - mu) * rs * ln_scale[c1_] + ln_bias[c1_];
        orow[i] = pack_bf16x2(silu_f(y0) * g[c0_], silu_f(y1) * g[c1_]);
    }

    __syncthreads();

    // ---- phase 2: segmented reduction over receivers in this block ----
    const int r0 = lds_r[0];
    const int r1 = lds_r[255];
    const int total = (r1 - r0 + 1) << 5;   // (#receivers) * 32 channels

    for (int p = t; p < total; p += 256) {
        const int n  = r0 + (p >> 5);
        const int ch = p & 31;
        int b  = offsets[n];
        int en = offsets[n + 1];
        const bool interior = (b >= B0) && (en <= B0 + 256);
        if (b < B0) b = B0;
        if (en > B0 + 256) en = B0 + 256;

        const int dw  = ch >> 1;
        const bool hi = (ch & 1);
        float sum = 0.0f;
        for (int q = b - B0; q < en - B0; ++q) {
            const unsigned u = lds_u[q * LDS_USTR + dw];
            sum += __uint_as_float(hi ? (u & 0xFFFF0000u) : (u << 16));
        }

        float* dst = msg + (size_t)n * MSG_C + ch;
        if (interior)       *dst = sum;          // sole owner (incl. empty = 0)
        else if (en > b)    atomicAdd(dst, sum); // straddling segment part
    }
}

// ---------------------------------------------------------------------------
// Fallback (tiny ws): R1 atomic edge kernel
// ---------------------------------------------------------------------------
__global__ __launch_bounds__(256) void edge_kernel(
    const float* __restrict__ proj, const float* __restrict__ e_embed,
    const int* __restrict__ senders, const int* __restrict__ receivers,
    const float* __restrict__ ln_scale, const float* __restrict__ ln_bias,
    const float* __restrict__ W_e, float* __restrict__ msg)
{
    const int e = blockIdx.x * blockDim.x + threadIdx.x;
    if (e >= N_NN_C) return;
    const int s = senders[e];
    const int r = receivers[e];
    const float4* ps = reinterpret_cast<const float4*>(proj + (size_t)s * MSG_C);
    const float4* pq = reinterpret_cast<const float4*>(proj + (size_t)(N_NUC_C + r) * MSG_C);
    float x[MSG_C];
    #pragma unroll
    for (int q = 0; q < 8; ++q) {
        const float4 a = ps[q];
        const float4 b = pq[q];
        x[4*q+0] = a.x + b.x; x[4*q+1] = a.y + b.y;
        x[4*q+2] = a.z + b.z; x[4*q+3] = a.w + b.w;
    }
    float mu = 0.0f;
    #pragma unroll
    for (int c = 0; c < MSG_C; ++c) mu += x[c];
    mu *= (1.0f / MSG_C);
    float var = 0.0f;
    #pragma unroll
    for (int c = 0; c < MSG_C; ++c) { const float d = x[c] - mu; var = fmaf(d, d, var); }
    var *= (1.0f / MSG_C);
    const float rs = rsqrtf(var + 1e-6f);
    #pragma unroll
    for (int c = 0; c < MSG_C; ++c) {
        const float y = (x[c] - mu) * rs * ln_scale[c] + ln_bias[c];
        x[c] = silu_f(y);
    }
    float ev[MSG_C];
    const float4* ee = reinterpret_cast<const float4*>(e_embed + (size_t)e * MSG_C);
    #pragma unroll
    for (int q = 0; q < 8; ++q) {
        const float4 v = ee[q];
        ev[4*q+0] = v.x; ev[4*q+1] = v.y; ev[4*q+2] = v.z; ev[4*q+3] = v.w;
    }
    float g[MSG_C];
    #pragma unroll
    for (int c = 0; c < MSG_C; ++c) g[c] = 0.0f;
    #pragma unroll
    for (int k = 0; k < MSG_C; ++k) {
        const float ek = ev[k];
        #pragma unroll
        for (int c = 0; c < MSG_C; ++c) g[c] = fmaf(ek, W_e[k * MSG_C + c], g[c]);
    }
    float* mrow = msg + (size_t)r * MSG_C;
    #pragma unroll
    for (int c = 0; c < MSG_C; ++c) atomicAdd(mrow + c, x[c] * g[c]);
}

// ---------------------------------------------------------------------------
// Kernel C: out[n][j] = silu( (msg[n] . W_out[:,j]) * norm[n] )
// ---------------------------------------------------------------------------
__global__ __launch_bounds__(256) void out_kernel(
    const float* __restrict__ msg, const float* __restrict__ norm,
    const float* __restrict__ W_out, float* __restrict__ out)
{
    const int j     = threadIdx.x & (OUT_C - 1);
    const int local = threadIdx.x >> 7;

    float w[MSG_C];
    #pragma unroll
    for (int k = 0; k < MSG_C; ++k) w[k] = W_out[k * OUT_C + j];

    for (int n = blockIdx.x * 2 + local; n < N_NUC_C; n += gridDim.x * 2) {
        const float4* m4 = reinterpret_cast<const float4*>(msg + (size_t)n * MSG_C);
        float acc = 0.0f;
        #pragma unroll
        for (int q = 0; q < 8; ++q) {
            const float4 mv = m4[q];
            acc = fmaf(mv.x, w[4*q+0], acc);
            acc = fmaf(mv.y, w[4*q+1], acc);
            acc = fmaf(mv.z, w[4*q+2], acc);
            acc = fmaf(mv.w, w[4*q+3], acc);
        }
        acc *= norm[n];
        out[(size_t)n * OUT_C + j] = silu_f(acc);
    }
}

extern "C" void kernel_launch(void* const* d_in, const int* in_sizes, int n_in,
                              void* d_out, int out_size, void* d_ws, size_t ws_size,
                              hipStream_t stream) {
    const float* s_embed   = (const float*)d_in[0];
    const float* r_embed   = (const float*)d_in[1];
    const float* e_embed   = (const float*)d_in[2];
    const float* norm      = (const float*)d_in[3];
    const int*   senders   = (const int*)d_in[4];
    const int*   receivers = (const int*)d_in[5];
    const float* W_s       = (const float*)d_in[6];
    const float* b_s       = (const float*)d_in[7];
    const float* W_r       = (const float*)d_in[8];
    const float* b_r       = (const float*)d_in[9];
    const float* ln_scale  = (const float*)d_in[10];
    const float* ln_bias   = (const float*)d_in[11];
    const float* W_e       = (const float*)d_in[12];
    const float* W_out     = (const float*)d_in[13];
    float* out = (float*)d_out;

    char* ws = (char*)d_ws;
    size_t off = 0;
    auto alloc = [&](size_t bytes) { char* p = ws + off; off += (bytes + 255) & ~(size_t)255; return p; };

    float* proj      = (float*)alloc((size_t)2 * N_NUC_C * MSG_C * 4); // 25.6 MB
    float* msg       = (float*)alloc((size_t)N_NUC_C * MSG_C * 4);     // 12.8 MB
    const size_t off_min = off;                                        // 38.4 MB
    int*   cnt       = (int*)  alloc((size_t)N_NUC_C * 4);
    int*   excl      = (int*)  alloc((size_t)N_NUC_C * 4);
    int*   offsets   = (int*)  alloc((size_t)(N_NUC_C + 1) * 4);
    int*   blockTot  = (int*)  alloc(128 * 4);
    int*   blockOff  = (int*)  alloc(128 * 4);
    int*   rank      = (int*)  alloc((size_t)N_NN_C * 4);              // 6.4 MB
    int2*  pack_csr  = (int2*) alloc((size_t)N_NN_C * 8);              // 12.8 MB
    uint4* e_csr     = (uint4*)alloc((size_t)N_NN_C * 64);             // 102.4 MB
    const size_t off_full = off;                                       // ~161 MB

    dim3 pgrid((N_NUC_C + 255) / 256, 4);
    proj_kernel<<<pgrid, 256, 0, stream>>>(s_embed, r_embed, W_s, b_s, W_r, b_r, proj);

    if (off_full <= ws_size) {
        // --- CSR (1 atomic pass) + partition-local scatter w/ e_embed repack
        //     + fused edge-compute/in-block-reduce (all-sequential reads) ---
        hipMemsetAsync(cnt, 0, (size_t)N_NUC_C * 4, stream);
        hipMemsetAsync(msg, 0, (size_t)N_NUC_C * MSG_C * 4, stream);
        rank_kernel<<<(N_NN_C + 255) / 256, 256, 0, stream>>>(receivers, cnt, rank);
        scan1_kernel<<<NB1, 256, 0, stream>>>(cnt, excl, blockTot);
        scan2_kernel<<<1, 128, 0, stream>>>(blockTot, blockOff);
        scan3_kernel<<<(N_NUC_C + 255) / 256, 256, 0, stream>>>(excl, blockOff, offsets);
        scatter_pack8_kernel<<<NPART * SBLK, 256, 0, stream>>>(
            senders, receivers, rank, offsets, e_embed, pack_csr, e_csr);
        fused_csr_kernel<<<N_NN_C / 256, 256, 0, stream>>>(
            proj, pack_csr, e_csr, offsets, ln_scale, ln_bias, W_e, msg);
    } else if (off_min <= ws_size) {
        // --- fallback: R1 atomic path ---
        hipMemsetAsync(msg, 0, (size_t)N_NUC_C * MSG_C * 4, stream);
        edge_kernel<<<(N_NN_C + 255) / 256, 256, 0, stream>>>(
            proj, e_embed, senders, receivers, ln_scale, ln_bias, W_e, msg);
    }

    out_kernel<<<2048, 256, 0, stream>>>(msg, norm, W_out, out);
}

// Round 9
// 390.780 us; speedup vs baseline: 1.2505x; 1.2505x over previous
//
#include <hip/hip_runtime.h>
#include <hip/hip_bf16.h>
#include <math.h>

#define N_NUC_C 100000
#define N_NN_C  1600000
#define EMB_C   128
#define MSG_C   32
#define OUT_C   128
#define NB1     98   // ceil(N_NUC / 1024) for the scan
#define NPART   8
#define R_PER_P (N_NUC_C / NPART)          // 12500 receivers per partition
#define SBLK    784                        // blocks per partition in scatter
#define STHREADS (SBLK * 256)              // 200704 threads per partition
#define LDS_USTR 17                        // uint row stride (16 packed + 1 pad, odd -> conflict-free)

__device__ __forceinline__ float silu_f(float y) {
    return y / (1.0f + __expf(-y));
}

// round-to-nearest-even f32->bf16, packed pair (a -> low 16, b -> high 16)
__device__ __forceinline__ unsigned pack_bf16x2(float a, float b) {
    unsigned ua = __float_as_uint(a); ua += 0x7FFFu + ((ua >> 16) & 1u);
    unsigned ub = __float_as_uint(b); ub += 0x7FFFu + ((ub >> 16) & 1u);
    return (ua >> 16) | (ub & 0xFFFF0000u);
}

// ---------------------------------------------------------------------------
// Kernel A: node projections  proj[pr][n][c] = embed[n] @ W + b
// ---------------------------------------------------------------------------
__global__ __launch_bounds__(256) void proj_kernel(
    const float* __restrict__ s_embed, const float* __restrict__ r_embed,
    const float* __restrict__ W_s, const float* __restrict__ b_s,
    const float* __restrict__ W_r, const float* __restrict__ b_r,
    float* __restrict__ proj /* [2][N_NUC][MSG] */)
{
    const int n   = blockIdx.x * blockDim.x + threadIdx.x;
    const int sub = blockIdx.y;       // 0..3
    const int pr  = sub >> 1;
    const int c0  = (sub & 1) * 16;
    if (n >= N_NUC_C) return;

    const float* __restrict__ src = pr ? r_embed : s_embed;
    const float* __restrict__ W   = pr ? W_r : W_s;
    const float* __restrict__ b   = pr ? b_r : b_s;
    float* __restrict__ dst = proj + (size_t)pr * N_NUC_C * MSG_C;

    float acc[16];
    #pragma unroll
    for (int i = 0; i < 16; ++i) acc[i] = b[c0 + i];

    const float* row = src + (size_t)n * EMB_C;
    #pragma unroll 4
    for (int k = 0; k < EMB_C; k += 4) {
        const float4 rv = *reinterpret_cast<const float4*>(row + k);
        #pragma unroll
        for (int i = 0; i < 16; ++i) {
            acc[i] = fmaf(rv.x, W[(k + 0) * MSG_C + c0 + i], acc[i]);
            acc[i] = fmaf(rv.y, W[(k + 1) * MSG_C + c0 + i], acc[i]);
            acc[i] = fmaf(rv.z, W[(k + 2) * MSG_C + c0 + i], acc[i]);
            acc[i] = fmaf(rv.w, W[(k + 3) * MSG_C + c0 + i], acc[i]);
        }
    }

    float4* d = reinterpret_cast<float4*>(dst + (size_t)n * MSG_C + c0);
    d[0] = make_float4(acc[0],  acc[1],  acc[2],  acc[3]);
    d[1] = make_float4(acc[4],  acc[5],  acc[6],  acc[7]);
    d[2] = make_float4(acc[8],  acc[9],  acc[10], acc[11]);
    d[3] = make_float4(acc[12], acc[13], acc[14], acc[15]);
}

// ---------------------------------------------------------------------------
// Fused CSR-rank pass + e_embed bf16 repack. All I/O sequential; the 1.6M
// random rank atomics hide under the ~330 MB stream.
// ---------------------------------------------------------------------------
__global__ __launch_bounds__(256) void rank_pack_kernel(
    const int* __restrict__ receivers, const float* __restrict__ e_embed,
    int* __restrict__ cnt, int* __restrict__ rank,
    uint4* __restrict__ e_bf16 /* [N_NN][4] */)
{
    const int e = blockIdx.x * blockDim.x + threadIdx.x;
    if (e >= N_NN_C) return;

    // bf16 repack (sequential read + sequential write)
    const float4* ee = reinterpret_cast<const float4*>(e_embed + (size_t)e * MSG_C);
    uint4* d4 = e_bf16 + (size_t)e * 4;
    #pragma unroll
    for (int q = 0; q < 4; ++q) {
        const float4 a = ee[2*q];
        const float4 b = ee[2*q + 1];
        uint4 w;
        w.x = pack_bf16x2(a.x, a.y);
        w.y = pack_bf16x2(a.z, a.w);
        w.z = pack_bf16x2(b.x, b.y);
        w.w = pack_bf16x2(b.z, b.w);
        d4[q] = w;
    }

    // CSR rank (random atomic, overlapped with the stream)
    rank[e] = atomicAdd(&cnt[receivers[e]], 1);
}

// Exclusive scan of cnt[N_NUC] -> offsets. Three tiny kernels.
__global__ __launch_bounds__(256) void scan1_kernel(
    const int* __restrict__ cnt, int* __restrict__ excl, int* __restrict__ blockTot)
{
    __shared__ int waveTot[4];
    const int t = threadIdx.x, b = blockIdx.x;
    const int lane = t & 63, wid = t >> 6;
    const int base = b * 1024 + t * 4;

    int d0 = (base + 0 < N_NUC_C) ? cnt[base + 0] : 0;
    int d1 = (base + 1 < N_NUC_C) ? cnt[base + 1] : 0;
    int d2 = (base + 2 < N_NUC_C) ? cnt[base + 2] : 0;
    int d3 = (base + 3 < N_NUC_C) ? cnt[base + 3] : 0;
    const int s = d0 + d1 + d2 + d3;

    int incl = s;
    #pragma unroll
    for (int off = 1; off < 64; off <<= 1) {
        int v = __shfl_up(incl, off);
        if (lane >= off) incl += v;
    }
    const int wexcl = incl - s;
    if (lane == 63) waveTot[wid] = incl;
    __syncthreads();
    int wbase = 0;
    for (int w = 0; w < wid; ++w) wbase += waveTot[w];
    const int e0 = wbase + wexcl;

    if (base + 0 < N_NUC_C) excl[base + 0] = e0;
    if (base + 1 < N_NUC_C) excl[base + 1] = e0 + d0;
    if (base + 2 < N_NUC_C) excl[base + 2] = e0 + d0 + d1;
    if (base + 3 < N_NUC_C) excl[base + 3] = e0 + d0 + d1 + d2;
    if (t == 255) blockTot[b] = wbase + incl;
}

__global__ __launch_bounds__(128) void scan2_kernel(
    const int* __restrict__ blockTot, int* __restrict__ blockOff)
{
    __shared__ int sh[128];
    const int t = threadIdx.x;
    const int v = (t < NB1) ? blockTot[t] : 0;
    sh[t] = v;
    __syncthreads();
    #pragma unroll
    for (int off = 1; off < 128; off <<= 1) {
        int x = 0;
        if (t >= off) x = sh[t - off];
        __syncthreads();
        sh[t] += x;
        __syncthreads();
    }
    if (t < NB1) blockOff[t] = sh[t] - v;
}

__global__ __launch_bounds__(256) void scan3_kernel(
    const int* __restrict__ excl, const int* __restrict__ blockOff,
    int* __restrict__ offsets)
{
    const int n = blockIdx.x * blockDim.x + threadIdx.x;
    if (n < N_NUC_C) offsets[n] = excl[n] + blockOff[n >> 10];
    if (n == 0) offsets[N_NUC_C] = N_NN_C;
}

// ---------------------------------------------------------------------------
// Partition-local ATOMIC-FREE scatter (R7 version): 8 receiver ranges; blocks
// with blockIdx%8==p scan all edges (coalesced) and write int4 (e,s,r,0) to
// dst = offsets[r] + rank[e]. Partition-clustered -> L2 write coalescing.
// ---------------------------------------------------------------------------
__global__ __launch_bounds__(256) void scatter_pack8_kernel(
    const int* __restrict__ senders, const int* __restrict__ receivers,
    const int* __restrict__ rank, const int* __restrict__ offsets,
    int4* __restrict__ edge_pack)
{
    const int p    = blockIdx.x & 7;
    const int blk  = blockIdx.x >> 3;                 // 0..SBLK-1
    const int base = blk * 256 + threadIdx.x;         // 0..STHREADS-1
    const int rlo  = p * R_PER_P;
    const int rhi  = rlo + R_PER_P;

    #pragma unroll
    for (int k = 0; k < 8; ++k) {
        const int e = base + k * STHREADS;
        if (e < N_NN_C) {
            const int r = receivers[e];
            if (r >= rlo && r < rhi) {
                const int dst = offsets[r] + rank[e];
                edge_pack[dst] = make_int4(e, senders[e], r, 0);
            }
        }
    }
}

// ---------------------------------------------------------------------------
// Fused CSR edge compute + in-block segmented reduction.
// Random reads: e_bf16[e] (64 B, HALF of R7's 128 B) + proj_s (L2/L3).
// Messages staged in LDS bf16x2 (uint[256][17], conflict-free). Reduce in f32.
// ---------------------------------------------------------------------------
__global__ __launch_bounds__(256) void fused_csr_kernel(
    const float* __restrict__ proj,      // [2][N_NUC][MSG]
    const uint4* __restrict__ e_bf16,    // [N_NN][4] bf16 rows, ORIGINAL order
    const int4*  __restrict__ edge_pack, // [N_NN] (e, s, r, 0) CSR order
    const int*   __restrict__ offsets,   // [N_NUC+1]
    const float* __restrict__ ln_scale,
    const float* __restrict__ ln_bias,
    const float* __restrict__ W_e,       // [MSG][MSG]
    float*       __restrict__ msg)       // [N_NUC][MSG], pre-zeroed
{
    __shared__ unsigned lds_u[256 * LDS_USTR];
    __shared__ int      lds_r[256];

    const int t  = threadIdx.x;
    const int B0 = blockIdx.x * 256;     // first slot of this block

    // ---- phase 1: per-edge message (single-shot, straight-line) ----
    const int4 pk = edge_pack[B0 + t];
    const int e = pk.x, s = pk.y, r = pk.z;
    lds_r[t] = r;

    // random 64 B read of the bf16 edge row
    float ev[MSG_C];
    {
        const uint4* ec = e_bf16 + (size_t)e * 4;
        #pragma unroll
        for (int q = 0; q < 4; ++q) {
            const uint4 w = ec[q];
            ev[8*q+0] = __uint_as_float(w.x << 16);
            ev[8*q+1] = __uint_as_float(w.x & 0xFFFF0000u);
            ev[8*q+2] = __uint_as_float(w.y << 16);
            ev[8*q+3] = __uint_as_float(w.y & 0xFFFF0000u);
            ev[8*q+4] = __uint_as_float(w.z << 16);
            ev[8*q+5] = __uint_as_float(w.z & 0xFFFF0000u);
            ev[8*q+6] = __uint_as_float(w.w << 16);
            ev[8*q+7] = __uint_as_float(w.w & 0xFFFF0000u);
        }
    }

    const float4* ps = reinterpret_cast<const float4*>(proj + (size_t)s * MSG_C);
    const float4* pq = reinterpret_cast<const float4*>(proj + (size_t)(N_NUC_C + r) * MSG_C);

    float x[MSG_C];
    #pragma unroll
    for (int q = 0; q < 8; ++q) {
        const float4 a = ps[q];
        const float4 b = pq[q];
        x[4*q+0] = a.x + b.x; x[4*q+1] = a.y + b.y;
        x[4*q+2] = a.z + b.z; x[4*q+3] = a.w + b.w;
    }

    // gate = e @ W_e (wave-uniform W_e -> scalar operands)
    float g[MSG_C];
    #pragma unroll
    for (int c = 0; c < MSG_C; ++c) g[c] = 0.0f;
    #pragma unroll
    for (int k = 0; k < MSG_C; ++k) {
        const float ek = ev[k];
        #pragma unroll
        for (int c = 0; c < MSG_C; ++c)
            g[c] = fmaf(ek, W_e[k * MSG_C + c], g[c]);
    }

    // LayerNorm + SiLU, write packed bf16 message to LDS
    float mu = 0.0f;
    #pragma unroll
    for (int c = 0; c < MSG_C; ++c) mu += x[c];
    mu *= (1.0f / MSG_C);
    float var = 0.0f;
    #pragma unroll
    for (int c = 0; c < MSG_C; ++c) { const float d = x[c] - mu; var = fmaf(d, d, var); }
    var *= (1.0f / MSG_C);
    const float rs = rsqrtf(var + 1e-6f);

    unsigned* orow = &lds_u[t * LDS_USTR];
    #pragma unroll
    for (int i = 0; i < 16; ++i) {
        const int c0_ = 2*i, c1_ = 2*i + 1;
        const float y0 = (x[c0_] - mu) * rs * ln_scale[c0_] + ln_bias[c0_];
        const float y1 = (x[c1_] - mu) * rs * ln_scale[c1_] + ln_bias[c1_];
        orow[i] = pack_bf16x2(silu_f(y0) * g[c0_], silu_f(y1) * g[c1_]);
    }

    __syncthreads();

    // ---- phase 2: segmented reduction over receivers in this block ----
    const int r0 = lds_r[0];
    const int r1 = lds_r[255];
    const int total = (r1 - r0 + 1) << 5;   // (#receivers) * 32 channels

    for (int p = t; p < total; p += 256) {
        const int n  = r0 + (p >> 5);
        const int ch = p & 31;
        int b  = offsets[n];
        int en = offsets[n + 1];
        const bool interior = (b >= B0) && (en <= B0 + 256);
        if (b < B0) b = B0;
        if (en > B0 + 256) en = B0 + 256;

        const int dw  = ch >> 1;
        const bool hi = (ch & 1);
        float sum = 0.0f;
        for (int q = b - B0; q < en - B0; ++q) {
            const unsigned u = lds_u[q * LDS_USTR + dw];
            sum += __uint_as_float(hi ? (u & 0xFFFF0000u) : (u << 16));
        }

        float* dst = msg + (size_t)n * MSG_C + ch;
        if (interior)       *dst = sum;          // sole owner (incl. empty = 0)
        else if (en > b)    atomicAdd(dst, sum); // straddling segment part
    }
}

// ---------------------------------------------------------------------------
// Fallback (tiny ws): R1 atomic edge kernel
// ---------------------------------------------------------------------------
__global__ __launch_bounds__(256) void edge_kernel(
    const float* __restrict__ proj, const float* __restrict__ e_embed,
    const int* __restrict__ senders, const int* __restrict__ receivers,
    const float* __restrict__ ln_scale, const float* __restrict__ ln_bias,
    const float* __restrict__ W_e, float* __restrict__ msg)
{
    const int e = blockIdx.x * blockDim.x + threadIdx.x;
    if (e >= N_NN_C) return;
    const int s = senders[e];
    const int r = receivers[e];
    const float4* ps = reinterpret_cast<const float4*>(proj + (size_t)s * MSG_C);
    const float4* pq = reinterpret_cast<const float4*>(proj + (size_t)(N_NUC_C + r) * MSG_C);
    float x[MSG_C];
    #pragma unroll
    for (int q = 0; q < 8; ++q) {
        const float4 a = ps[q];
        const float4 b = pq[q];
        x[4*q+0] = a.x + b.x; x[4*q+1] = a.y + b.y;
        x[4*q+2] = a.z + b.z; x[4*q+3] = a.w + b.w;
    }
    float mu = 0.0f;
    #pragma unroll
    for (int c = 0; c < MSG_C; ++c) mu += x[c];
    mu *= (1.0f / MSG_C);
    float var = 0.0f;
    #pragma unroll
    for (int c = 0; c < MSG_C; ++c) { const float d = x[c] - mu; var = fmaf(d, d, var); }
    var *= (1.0f / MSG_C);
    const float rs = rsqrtf(var + 1e-6f);
    #pragma unroll
    for (int c = 0; c < MSG_C; ++c) {
        const float y = (x[c] - mu) * rs * ln_scale[c] + ln_bias[c];
        x[c] = silu_f(y);
    }
    float ev[MSG_C];
    const float4* ee = reinterpret_cast<const float4*>(e_embed + (size_t)e * MSG_C);
    #pragma unroll
    for (int q = 0; q < 8; ++q) {
        const float4 v = ee[q];
        ev[4*q+0] = v.x; ev[4*q+1] = v.y; ev[4*q+2] = v.z; ev[4*q+3] = v.w;
    }
    float g[MSG_C];
    #pragma unroll
    for (int c = 0; c < MSG_C; ++c) g[c] = 0.0f;
    #pragma unroll
    for (int k = 0; k < MSG_C; ++k) {
        const float ek = ev[k];
        #pragma unroll
        for (int c = 0; c < MSG_C; ++c) g[c] = fmaf(ek, W_e[k * MSG_C + c], g[c]);
    }
    float* mrow = msg + (size_t)r * MSG_C;
    #pragma unroll
    for (int c = 0; c < MSG_C; ++c) atomicAdd(mrow + c, x[c] * g[c]);
}

// ---------------------------------------------------------------------------
// Kernel C: out[n][j] = silu( (msg[n] . W_out[:,j]) * norm[n] )
// ---------------------------------------------------------------------------
__global__ __launch_bounds__(256) void out_kernel(
    const float* __restrict__ msg, const float* __restrict__ norm,
    const float* __restrict__ W_out, float* __restrict__ out)
{
    const int j     = threadIdx.x & (OUT_C - 1);
    const int local = threadIdx.x >> 7;

    float w[MSG_C];
    #pragma unroll
    for (int k = 0; k < MSG_C; ++k) w[k] = W_out[k * OUT_C + j];

    for (int n = blockIdx.x * 2 + local; n < N_NUC_C; n += gridDim.x * 2) {
        const float4* m4 = reinterpret_cast<const float4*>(msg + (size_t)n * MSG_C);
        float acc = 0.0f;
        #pragma unroll
        for (int q = 0; q < 8; ++q) {
            const float4 mv = m4[q];
            acc = fmaf(mv.x, w[4*q+0], acc);
            acc = fmaf(mv.y, w[4*q+1], acc);
            acc = fmaf(mv.z, w[4*q+2], acc);
            acc = fmaf(mv.w, w[4*q+3], acc);
        }
        acc *= norm[n];
        out[(size_t)n * OUT_C + j] = silu_f(acc);
    }
}

extern "C" void kernel_launch(void* const* d_in, const int* in_sizes, int n_in,
                              void* d_out, int out_size, void* d_ws, size_t ws_size,
                              hipStream_t stream) {
    const float* s_embed   = (const float*)d_in[0];
    const float* r_embed   = (const float*)d_in[1];
    const float* e_embed   = (const float*)d_in[2];
    const float* norm      = (const float*)d_in[3];
    const int*   senders   = (const int*)d_in[4];
    const int*   receivers = (const int*)d_in[5];
    const float* W_s       = (const float*)d_in[6];
    const float* b_s       = (const float*)d_in[7];
    const float* W_r       = (const float*)d_in[8];
    const float* b_r       = (const float*)d_in[9];
    const float* ln_scale  = (const float*)d_in[10];
    const float* ln_bias   = (const float*)d_in[11];
    const float* W_e       = (const float*)d_in[12];
    const float* W_out     = (const float*)d_in[13];
    float* out = (float*)d_out;

    char* ws = (char*)d_ws;
    size_t off = 0;
    auto alloc = [&](size_t bytes) { char* p = ws + off; off += (bytes + 255) & ~(size_t)255; return p; };

    float* proj      = (float*)alloc((size_t)2 * N_NUC_C * MSG_C * 4); // 25.6 MB
    float* msg       = (float*)alloc((size_t)N_NUC_C * MSG_C * 4);     // 12.8 MB
    const size_t off_min = off;                                        // 38.4 MB
    int*   cnt       = (int*)  alloc((size_t)N_NUC_C * 4);
    int*   excl      = (int*)  alloc((size_t)N_NUC_C * 4);
    int*   offsets   = (int*)  alloc((size_t)(N_NUC_C + 1) * 4);
    int*   blockTot  = (int*)  alloc(128 * 4);
    int*   blockOff  = (int*)  alloc(128 * 4);
    int*   rank      = (int*)  alloc((size_t)N_NN_C * 4);              // 6.4 MB
    int4*  edge_pack = (int4*) alloc((size_t)N_NN_C * 16);             // 25.6 MB
    uint4* e_bf16    = (uint4*)alloc((size_t)N_NN_C * 64);             // 102.4 MB
    const size_t off_full = off;                                       // ~174 MB

    dim3 pgrid((N_NUC_C + 255) / 256, 4);
    proj_kernel<<<pgrid, 256, 0, stream>>>(s_embed, r_embed, W_s, b_s, W_r, b_r, proj);

    if (off_full <= ws_size) {
        // --- rank+bf16-repack (all streaming) + scan + partition scatter +
        //     fused edge-compute/in-block-reduce (64 B random reads) ---
        hipMemsetAsync(cnt, 0, (size_t)N_NUC_C * 4, stream);
        hipMemsetAsync(msg, 0, (size_t)N_NUC_C * MSG_C * 4, stream);
        rank_pack_kernel<<<(N_NN_C + 255) / 256, 256, 0, stream>>>(
            receivers, e_embed, cnt, rank, e_bf16);
        scan1_kernel<<<NB1, 256, 0, stream>>>(cnt, excl, blockTot);
        scan2_kernel<<<1, 128, 0, stream>>>(blockTot, blockOff);
        scan3_kernel<<<(N_NUC_C + 255) / 256, 256, 0, stream>>>(excl, blockOff, offsets);
        scatter_pack8_kernel<<<NPART * SBLK, 256, 0, stream>>>(
            senders, receivers, rank, offsets, edge_pack);
        fused_csr_kernel<<<N_NN_C / 256, 256, 0, stream>>>(
            proj, e_bf16, edge_pack, offsets, ln_scale, ln_bias, W_e, msg);
    } else if (off_min <= ws_size) {
        // --- fallback: R1 atomic path ---
        hipMemsetAsync(msg, 0, (size_t)N_NUC_C * MSG_C * 4, stream);
        edge_kernel<<<(N_NN_C + 255) / 256, 256, 0, stream>>>(
            proj, e_embed, senders, receivers, ln_scale, ln_bias, W_e, msg);
    }

    out_kernel<<<2048, 256, 0, stream>>>(msg, norm, W_out, out);
}